// Round 1
// baseline (325.711 us; speedup 1.0000x reference)
//
#include <hip/hip_runtime.h>
#include <math.h>

#define BATCH 65536
#define DT_C 0.0166667f
#define NN_RATIO_C 0.3f

__device__ __forceinline__ float lrelu(float x) {
    return x > 0.0f ? x : 0.01f * x;
}

__global__ __launch_bounds__(256) void joint_kernel(
    const float* __restrict__ SS, const float* __restrict__ Alphas,
    const float* __restrict__ K0s, const float* __restrict__ K1s,
    const float* __restrict__ L0s, const float* __restrict__ L1s,
    const float* __restrict__ Ms, const float* __restrict__ Ivec,
    const float* __restrict__ Bv, const float* __restrict__ Kv,
    const float* __restrict__ W1, const float* __restrict__ b1,
    const float* __restrict__ W2, const float* __restrict__ b2,
    const float* __restrict__ W3, const float* __restrict__ b3,
    const float* __restrict__ W4, const float* __restrict__ b4,
    float* __restrict__ out)
{
    int b = blockIdx.x * blockDim.x + threadIdx.x;
    if (b >= BATCH) return;

    float s0 = SS[2 * b];
    float s1 = SS[2 * b + 1];
    float I  = Ivec[0];
    float bv = Bv[0];
    float kv = Kv[0];
    float inv_I = 1.0f / I;

    float Ksum = 0.0f, BFsum = 0.0f;

    // m-loop kept rolled: weight indices are wave-uniform -> scalar loads;
    // unrolling 8x would blow I-cache (~10KB body).
    #pragma unroll 1
    for (int m = 0; m < 8; ++m) {
        float a = Alphas[8 * b + m];
        a = fminf(fmaxf(a, 0.0f), 1.0f);
        float ms = Ms[m];
        float l  = s0 * ms;
        float dl = s1 * ms;

        float h[32], hn[32];
        const float* w1  = W1 + m * 96;
        const float* bb1 = b1 + m * 32;
        #pragma unroll
        for (int o = 0; o < 32; ++o) {
            float acc = bb1[o] + w1[o * 3 + 0] * l + w1[o * 3 + 1] * dl + w1[o * 3 + 2] * a;
            h[o] = lrelu(acc);
        }

        const float* w2  = W2 + m * 1024;
        const float* bb2 = b2 + m * 32;
        #pragma unroll
        for (int o = 0; o < 32; ++o) {
            float acc = bb2[o];
            #pragma unroll
            for (int i = 0; i < 32; ++i) acc += w2[o * 32 + i] * h[i];
            hn[o] = lrelu(acc);
        }

        const float* w3  = W3 + m * 1024;
        const float* bb3 = b3 + m * 32;
        #pragma unroll
        for (int o = 0; o < 32; ++o) {
            float acc = bb3[o];
            #pragma unroll
            for (int i = 0; i < 32; ++i) acc += w3[o * 32 + i] * hn[i];
            h[o] = lrelu(acc);
        }

        const float* w4 = W4 + m * 32;
        float acc = b4[m];
        #pragma unroll
        for (int i = 0; i < 32; ++i) acc += w4[i] * h[i];
        float nn_out = tanhf(acc) * NN_RATIO_C;

        float k0 = K0s[m], k1 = K1s[m], l0 = L0s[m], l1 = L1s[m];
        float kk = k0 + k1 * a;
        Ksum += kk * ms * ms;
        float BF = kk * (l0 + l1 * a - fabsf(l)) + k1 * l1 * a * a * nn_out;
        BFsum += BF * ms;
    }

    float A10 = -(Ksum + kv) * inv_I;
    float D   = 2.0f * sqrtf(Ksum * I);
    float A11 = -(D + bv) * inv_I;
    float B10 = BFsum * inv_I;

    // Reduced 3x3 expm: M = [[0, DT, 0],[A10*DT, A11*DT, B10*DT],[0,0,0]]
    // E = [[e^{A DT}, Phi1*c],[0,1]];  SSout = E2*SS + t  (U=[1,0] collapses
    // Bd0@U+Bd1@U to E[:2,2]).  ||M|| < ~0.5 -> 16-term Taylor is fp32-exact.
    const float m01 = DT_C;
    const float m10 = A10 * DT_C, m11 = A11 * DT_C, m12 = B10 * DT_C;

    float p00 = 0.0f, p01 = m01, p02 = 0.0f;
    float p10 = m10,  p11 = m11, p12 = m12;
    float t00 = p00, t01 = p01, t02 = p02;
    float t10 = p10, t11 = p11, t12 = p12;
    #pragma unroll
    for (int k = 2; k <= 16; ++k) {
        float inv = 1.0f / (float)k;  // constant-folded under full unroll
        float q00 = (p01 * m10) * inv;             // m00 == 0, m02 == 0
        float q01 = (p00 * m01 + p01 * m11) * inv;
        float q02 = (p01 * m12) * inv;
        float q10 = (p11 * m10) * inv;
        float q11 = (p10 * m01 + p11 * m11) * inv;
        float q12 = (p11 * m12) * inv;
        p00 = q00; p01 = q01; p02 = q02;
        p10 = q10; p11 = q11; p12 = q12;
        t00 += p00; t01 += p01; t02 += p02;
        t10 += p10; t11 += p11; t12 += p12;
    }
    float E00 = 1.0f + t00, E01 = t01, c0 = t02;
    float E10 = t10,        E11 = 1.0f + t11, c1 = t12;

    float o0 = E00 * s0 + E01 * s1 + c0;
    float o1 = E10 * s0 + E11 * s1 + c1;

    // Output 0: SSout[:,0:1] -> B floats. Output 1: SSout[:,:,0] -> B x 2.
    out[b] = o0;
    out[BATCH + 2 * b]     = o0;
    out[BATCH + 2 * b + 1] = o1;
}

extern "C" void kernel_launch(void* const* d_in, const int* in_sizes, int n_in,
                              void* d_out, int out_size, void* d_ws, size_t ws_size,
                              hipStream_t stream) {
    const float* SS     = (const float*)d_in[0];
    const float* Alphas = (const float*)d_in[1];
    const float* K0s    = (const float*)d_in[2];
    const float* K1s    = (const float*)d_in[3];
    const float* L0s    = (const float*)d_in[4];
    const float* L1s    = (const float*)d_in[5];
    const float* Ms     = (const float*)d_in[6];
    const float* I      = (const float*)d_in[7];
    const float* Bv     = (const float*)d_in[8];
    const float* Kv     = (const float*)d_in[9];
    const float* W1     = (const float*)d_in[10];
    const float* b1     = (const float*)d_in[11];
    const float* W2     = (const float*)d_in[12];
    const float* b2     = (const float*)d_in[13];
    const float* W3     = (const float*)d_in[14];
    const float* b3     = (const float*)d_in[15];
    const float* W4     = (const float*)d_in[16];
    const float* b4     = (const float*)d_in[17];
    float* out = (float*)d_out;

    joint_kernel<<<BATCH / 256, 256, 0, stream>>>(
        SS, Alphas, K0s, K1s, L0s, L1s, Ms, I, Bv, Kv,
        W1, b1, W2, b2, W3, b3, W4, b4, out);
}

// Round 2
// 162.506 us; speedup vs baseline: 2.0043x; 2.0043x over previous
//
#include <hip/hip_runtime.h>
#include <math.h>

#define BATCH 65536
#define DT_C 0.0166667f
#define NN_RATIO_C 0.3f

__device__ __forceinline__ float lrelu(float x) {
    return x > 0.0f ? x : 0.01f * x;
}

// Block = 512 threads = 8 waves. Wave w handles muscle w for 64 batch
// elements -> m is wave-uniform (readfirstlane) so all weight loads stay
// scalar (s_load) and every MAC is v_fmac_f32 v,s,v. 1024 blocks -> 8192
// waves (vs 1024 before): fixes the 1-wave/SIMD starvation of round 1.
__global__ __launch_bounds__(512) void joint_kernel(
    const float* __restrict__ SS, const float* __restrict__ Alphas,
    const float* __restrict__ K0s, const float* __restrict__ K1s,
    const float* __restrict__ L0s, const float* __restrict__ L1s,
    const float* __restrict__ Ms, const float* __restrict__ Ivec,
    const float* __restrict__ Bv, const float* __restrict__ Kv,
    const float* __restrict__ W1, const float* __restrict__ b1,
    const float* __restrict__ W2, const float* __restrict__ b2,
    const float* __restrict__ W3, const float* __restrict__ b3,
    const float* __restrict__ W4, const float* __restrict__ b4,
    float* __restrict__ out)
{
    __shared__ float lds_k[8][64];   // muscle-m K contribution per element
    __shared__ float lds_bf[8][64];  // muscle-m B_F*Ms contribution

    const int lane = threadIdx.x & 63;
    const int m    = __builtin_amdgcn_readfirstlane(threadIdx.x >> 6);
    const int b    = blockIdx.x * 64 + lane;

    const float s0 = SS[2 * b];
    const float s1 = SS[2 * b + 1];

    float a = Alphas[8 * b + m];
    a = fminf(fmaxf(a, 0.0f), 1.0f);
    const float ms = Ms[m];
    const float l  = s0 * ms;
    const float dl = s1 * ms;

    float h[32], hn[32];
    const float* w1  = W1 + m * 96;
    const float* bb1 = b1 + m * 32;
    #pragma unroll
    for (int o = 0; o < 32; ++o) {
        float acc = bb1[o] + w1[o * 3 + 0] * l + w1[o * 3 + 1] * dl + w1[o * 3 + 2] * a;
        h[o] = lrelu(acc);
    }

    const float* w2  = W2 + m * 1024;
    const float* bb2 = b2 + m * 32;
    #pragma unroll
    for (int o = 0; o < 32; ++o) {
        float acc = bb2[o];
        #pragma unroll
        for (int i = 0; i < 32; ++i) acc += w2[o * 32 + i] * h[i];
        hn[o] = lrelu(acc);
    }

    const float* w3  = W3 + m * 1024;
    const float* bb3 = b3 + m * 32;
    #pragma unroll
    for (int o = 0; o < 32; ++o) {
        float acc = bb3[o];
        #pragma unroll
        for (int i = 0; i < 32; ++i) acc += w3[o * 32 + i] * hn[i];
        h[o] = lrelu(acc);
    }

    const float* w4 = W4 + m * 32;
    float acc = b4[m];
    #pragma unroll
    for (int i = 0; i < 32; ++i) acc += w4[i] * h[i];

    // tanh(x) = 1 - 2/(e^{2x}+1) via v_exp_f32; plenty accurate vs 4.2e-2 thr.
    const float e2x = __expf(2.0f * acc);
    const float nn_out = (1.0f - 2.0f / (e2x + 1.0f)) * NN_RATIO_C;

    const float k0 = K0s[m], k1 = K1s[m], l0 = L0s[m], l1 = L1s[m];
    const float kk = k0 + k1 * a;
    lds_k[m][lane]  = kk * ms * ms;
    lds_bf[m][lane] = (kk * (l0 + l1 * a - fabsf(l)) + k1 * l1 * a * a * nn_out) * ms;

    __syncthreads();

    if (threadIdx.x < 64) {
        float Ksum = 0.0f, BFsum = 0.0f;
        #pragma unroll
        for (int mm = 0; mm < 8; ++mm) {
            Ksum  += lds_k[mm][lane];
            BFsum += lds_bf[mm][lane];
        }

        const float I  = Ivec[0];
        const float bv = Bv[0];
        const float kv = Kv[0];
        const float inv_I = 1.0f / I;

        const float A10 = -(Ksum + kv) * inv_I;
        const float D   = 2.0f * sqrtf(Ksum * I);
        const float A11 = -(D + bv) * inv_I;
        const float B10 = BFsum * inv_I;

        // Reduced 3x3 expm: M = [[0,DT,0],[A10*DT,A11*DT,B10*DT],[0,0,0]].
        // U=[1,0] collapses Bd0@U+Bd1@U to E[:2,2]. ||M||<~0.5 -> 16-term
        // Taylor is fp32-exact.
        const float m01 = DT_C;
        const float m10 = A10 * DT_C, m11 = A11 * DT_C, m12 = B10 * DT_C;

        float p00 = 0.0f, p01 = m01, p02 = 0.0f;
        float p10 = m10,  p11 = m11, p12 = m12;
        float t00 = p00, t01 = p01, t02 = p02;
        float t10 = p10, t11 = p11, t12 = p12;
        #pragma unroll
        for (int k = 2; k <= 16; ++k) {
            float inv = 1.0f / (float)k;  // constant-folded under full unroll
            float q00 = (p01 * m10) * inv;
            float q01 = (p00 * m01 + p01 * m11) * inv;
            float q02 = (p01 * m12) * inv;
            float q10 = (p11 * m10) * inv;
            float q11 = (p10 * m01 + p11 * m11) * inv;
            float q12 = (p11 * m12) * inv;
            p00 = q00; p01 = q01; p02 = q02;
            p10 = q10; p11 = q11; p12 = q12;
            t00 += p00; t01 += p01; t02 += p02;
            t10 += p10; t11 += p11; t12 += p12;
        }
        const float E00 = 1.0f + t00, E01 = t01, c0 = t02;
        const float E10 = t10,        E11 = 1.0f + t11, c1 = t12;

        const float o0 = E00 * s0 + E01 * s1 + c0;
        const float o1 = E10 * s0 + E11 * s1 + c1;

        out[b] = o0;                     // output 0: SSout[:,0:1]
        out[BATCH + 2 * b]     = o0;     // output 1: SSout[:,:,0]
        out[BATCH + 2 * b + 1] = o1;
    }
}

extern "C" void kernel_launch(void* const* d_in, const int* in_sizes, int n_in,
                              void* d_out, int out_size, void* d_ws, size_t ws_size,
                              hipStream_t stream) {
    const float* SS     = (const float*)d_in[0];
    const float* Alphas = (const float*)d_in[1];
    const float* K0s    = (const float*)d_in[2];
    const float* K1s    = (const float*)d_in[3];
    const float* L0s    = (const float*)d_in[4];
    const float* L1s    = (const float*)d_in[5];
    const float* Ms     = (const float*)d_in[6];
    const float* I      = (const float*)d_in[7];
    const float* Bv     = (const float*)d_in[8];
    const float* Kv     = (const float*)d_in[9];
    const float* W1     = (const float*)d_in[10];
    const float* b1     = (const float*)d_in[11];
    const float* W2     = (const float*)d_in[12];
    const float* b2     = (const float*)d_in[13];
    const float* W3     = (const float*)d_in[14];
    const float* b3     = (const float*)d_in[15];
    const float* W4     = (const float*)d_in[16];
    const float* b4     = (const float*)d_in[17];
    float* out = (float*)d_out;

    joint_kernel<<<BATCH / 64, 512, 0, stream>>>(
        SS, Alphas, K0s, K1s, L0s, L1s, Ms, I, Bv, Kv,
        W1, b1, W2, b2, W3, b3, W4, b4, out);
}

// Round 3
// 109.328 us; speedup vs baseline: 2.9792x; 1.4864x over previous
//
#include <hip/hip_runtime.h>
#include <math.h>

#define BATCH 65536
#define DT_C 0.0166667f
#define NN_RATIO_C 0.3f

typedef __bf16 bf16x8 __attribute__((ext_vector_type(8)));
typedef unsigned short us8 __attribute__((ext_vector_type(8)));
typedef unsigned short us4 __attribute__((ext_vector_type(4)));
typedef float f32x4 __attribute__((ext_vector_type(4)));

union FragU { us8 u; bf16x8 b; };

__device__ __forceinline__ unsigned short f2bf(float f) {
    unsigned u = __float_as_uint(f);
    u += 0x7FFFu + ((u >> 16) & 1u);   // round-to-nearest-even
    return (unsigned short)(u >> 16);
}
__device__ __forceinline__ float lrelu(float x) { return x > 0.0f ? x : 0.01f * x; }

// Block = 512 threads = 8 waves; wave w == muscle w; 64 batch rows per block.
// MLP layers as mfma_f32_16x16x32_bf16 with D[o][b] = sum_i W[o][i] * X[b][i]:
//   A-frag = W[o=t*16+(lane&15)][i=quad*8+j]  (contiguous in memory)
//   B-frag = X[b=lane&15][i=quad*8+j]         (contiguous in LDS, ds_read_b128)
//   D lane = col b=lane&15, rows o=quad*4+reg (o-consecutive -> ds_write_b64)
// LDS activation row stride = 40 halves (80B): 16B-aligned, <=2-way conflicts.
__global__ __launch_bounds__(512) void joint_kernel(
    const float* __restrict__ SS, const float* __restrict__ Alphas,
    const float* __restrict__ K0s, const float* __restrict__ K1s,
    const float* __restrict__ L0s, const float* __restrict__ L1s,
    const float* __restrict__ Ms, const float* __restrict__ Ivec,
    const float* __restrict__ Bv, const float* __restrict__ Kv,
    const float* __restrict__ W1, const float* __restrict__ b1,
    const float* __restrict__ W2, const float* __restrict__ b2,
    const float* __restrict__ W3, const float* __restrict__ b3,
    const float* __restrict__ W4, const float* __restrict__ b4,
    float* __restrict__ out)
{
    __shared__ unsigned short Xbuf[8][16 * 40];   // per-wave activation tile
    __shared__ float red_k[8][64];
    __shared__ float red_bf[8][64];

    const int tid  = threadIdx.x;
    const int lane = tid & 63;
    const int w    = tid >> 6;
    const int m    = __builtin_amdgcn_readfirstlane(w);
    const int n16  = lane & 15;
    const int quad = lane >> 4;

    const float ms = Ms[m];
    const float k0 = K0s[m], k1 = K1s[m], l0 = L0s[m], l1 = L1s[m];
    const float b4m = b4[m];

    // ---- weight fragments (loaded once per wave) ----
    FragU w1f[2], w2f[2], w3f[2];
    f32x4 bias1[2], bias2[2], bias3[2];
    #pragma unroll
    for (int t = 0; t < 2; ++t) {
        const int o = t * 16 + n16;
        const float* p2 = W2 + m * 1024 + o * 32 + quad * 8;
        const float* p3 = W3 + m * 1024 + o * 32 + quad * 8;
        f32x4 a2 = *(const f32x4*)p2, c2 = *(const f32x4*)(p2 + 4);
        f32x4 a3 = *(const f32x4*)p3, c3 = *(const f32x4*)(p3 + 4);
        #pragma unroll
        for (int j = 0; j < 4; ++j) {
            w2f[t].u[j] = f2bf(a2[j]); w2f[t].u[4 + j] = f2bf(c2[j]);
            w3f[t].u[j] = f2bf(a3[j]); w3f[t].u[4 + j] = f2bf(c3[j]);
        }
        us8 z = {0,0,0,0,0,0,0,0};
        w1f[t].u = z;
        if (quad == 0) {
            const float* p1 = W1 + m * 96 + o * 3;
            w1f[t].u[0] = f2bf(p1[0]);
            w1f[t].u[1] = f2bf(p1[1]);
            w1f[t].u[2] = f2bf(p1[2]);
        }
        bias1[t] = *(const f32x4*)(b1 + m * 32 + t * 16 + quad * 4);
        bias2[t] = *(const f32x4*)(b2 + m * 32 + t * 16 + quad * 4);
        bias3[t] = *(const f32x4*)(b3 + m * 32 + t * 16 + quad * 4);
    }
    const f32x4 w4a = *(const f32x4*)(W4 + m * 32 + quad * 4);
    const f32x4 w4b = *(const f32x4*)(W4 + m * 32 + 16 + quad * 4);

    unsigned short* X = &Xbuf[w][0];

    #pragma unroll 1
    for (int s = 0; s < 4; ++s) {
        const int bb = blockIdx.x * 64 + s * 16 + n16;
        const float s0v = SS[2 * bb];
        const float s1v = SS[2 * bb + 1];
        float av = Alphas[8 * bb + m];
        av = fminf(fmaxf(av, 0.0f), 1.0f);
        const float lv  = s0v * ms;
        const float dlv = s1v * ms;

        // layer-1 input fragment (K padded 3 -> 32)
        FragU xf;
        us8 z = {0,0,0,0,0,0,0,0};
        xf.u = z;
        if (quad == 0) { xf.u[0] = f2bf(lv); xf.u[1] = f2bf(dlv); xf.u[2] = f2bf(av); }

        f32x4 acc0 = bias1[0], acc1 = bias1[1];
        acc0 = __builtin_amdgcn_mfma_f32_16x16x32_bf16(w1f[0].b, xf.b, acc0, 0, 0, 0);
        acc1 = __builtin_amdgcn_mfma_f32_16x16x32_bf16(w1f[1].b, xf.b, acc1, 0, 0, 0);

        us4 st0, st1;
        #pragma unroll
        for (int r = 0; r < 4; ++r) {
            st0[r] = f2bf(lrelu(acc0[r]));
            st1[r] = f2bf(lrelu(acc1[r]));
        }
        *(us4*)&X[n16 * 40 + quad * 4]      = st0;   // o = 0..15
        *(us4*)&X[n16 * 40 + 16 + quad * 4] = st1;   // o = 16..31
        __asm__ volatile("s_waitcnt lgkmcnt(0)" ::: "memory");

        FragU hf;
        hf.u = *(const us8*)&X[n16 * 40 + quad * 8];
        acc0 = bias2[0]; acc1 = bias2[1];
        acc0 = __builtin_amdgcn_mfma_f32_16x16x32_bf16(w2f[0].b, hf.b, acc0, 0, 0, 0);
        acc1 = __builtin_amdgcn_mfma_f32_16x16x32_bf16(w2f[1].b, hf.b, acc1, 0, 0, 0);

        #pragma unroll
        for (int r = 0; r < 4; ++r) {
            st0[r] = f2bf(lrelu(acc0[r]));
            st1[r] = f2bf(lrelu(acc1[r]));
        }
        *(us4*)&X[n16 * 40 + quad * 4]      = st0;
        *(us4*)&X[n16 * 40 + 16 + quad * 4] = st1;
        __asm__ volatile("s_waitcnt lgkmcnt(0)" ::: "memory");

        hf.u = *(const us8*)&X[n16 * 40 + quad * 8];
        acc0 = bias3[0]; acc1 = bias3[1];
        acc0 = __builtin_amdgcn_mfma_f32_16x16x32_bf16(w3f[0].b, hf.b, acc0, 0, 0, 0);
        acc1 = __builtin_amdgcn_mfma_f32_16x16x32_bf16(w3f[1].b, hf.b, acc1, 0, 0, 0);

        // layer 4: dot over o (partials over this lane's 8 rows, butterfly over quads)
        float dot = 0.0f;
        #pragma unroll
        for (int r = 0; r < 4; ++r) {
            dot += lrelu(acc0[r]) * w4a[r];
            dot += lrelu(acc1[r]) * w4b[r];
        }
        dot += __shfl_xor(dot, 16, 64);
        dot += __shfl_xor(dot, 32, 64);

        if (quad == 0) {
            const float x2 = 2.0f * (dot + b4m);
            const float e2x = __expf(x2);
            const float nn = (1.0f - 2.0f / (e2x + 1.0f)) * NN_RATIO_C;
            const float kk = k0 + k1 * av;
            red_k[w][s * 16 + n16]  = kk * ms * ms;
            red_bf[w][s * 16 + n16] = (kk * (l0 + l1 * av - fabsf(lv)) + k1 * l1 * av * av * nn) * ms;
        }
    }

    __syncthreads();

    if (tid < 64) {
        float Ksum = 0.0f, BFsum = 0.0f;
        #pragma unroll
        for (int mm = 0; mm < 8; ++mm) {
            Ksum  += red_k[mm][tid];
            BFsum += red_bf[mm][tid];
        }

        const int b = blockIdx.x * 64 + tid;
        const float s0 = SS[2 * b];
        const float s1 = SS[2 * b + 1];
        const float I  = Ivec[0];
        const float bv = Bv[0];
        const float kv = Kv[0];
        const float inv_I = 1.0f / I;

        const float A10 = -(Ksum + kv) * inv_I;
        const float D   = 2.0f * sqrtf(Ksum * I);
        const float A11 = -(D + bv) * inv_I;
        const float B10 = BFsum * inv_I;

        // Reduced 3x3 expm (verified rounds 1-2): M=[[0,DT,0],[A10*DT,A11*DT,B10*DT],[0,0,0]]
        const float m01 = DT_C;
        const float m10 = A10 * DT_C, m11 = A11 * DT_C, m12 = B10 * DT_C;

        float p00 = 0.0f, p01 = m01, p02 = 0.0f;
        float p10 = m10,  p11 = m11, p12 = m12;
        float t00 = p00, t01 = p01, t02 = p02;
        float t10 = p10, t11 = p11, t12 = p12;
        #pragma unroll
        for (int k = 2; k <= 16; ++k) {
            float inv = 1.0f / (float)k;
            float q00 = (p01 * m10) * inv;
            float q01 = (p00 * m01 + p01 * m11) * inv;
            float q02 = (p01 * m12) * inv;
            float q10 = (p11 * m10) * inv;
            float q11 = (p10 * m01 + p11 * m11) * inv;
            float q12 = (p11 * m12) * inv;
            p00 = q00; p01 = q01; p02 = q02;
            p10 = q10; p11 = q11; p12 = q12;
            t00 += p00; t01 += p01; t02 += p02;
            t10 += p10; t11 += p11; t12 += p12;
        }
        const float E00 = 1.0f + t00, E01 = t01, c0 = t02;
        const float E10 = t10,        E11 = 1.0f + t11, c1 = t12;

        const float o0 = E00 * s0 + E01 * s1 + c0;
        const float o1 = E10 * s0 + E11 * s1 + c1;

        out[b] = o0;
        out[BATCH + 2 * b]     = o0;
        out[BATCH + 2 * b + 1] = o1;
    }
}

extern "C" void kernel_launch(void* const* d_in, const int* in_sizes, int n_in,
                              void* d_out, int out_size, void* d_ws, size_t ws_size,
                              hipStream_t stream) {
    const float* SS     = (const float*)d_in[0];
    const float* Alphas = (const float*)d_in[1];
    const float* K0s    = (const float*)d_in[2];
    const float* K1s    = (const float*)d_in[3];
    const float* L0s    = (const float*)d_in[4];
    const float* L1s    = (const float*)d_in[5];
    const float* Ms     = (const float*)d_in[6];
    const float* I      = (const float*)d_in[7];
    const float* Bv     = (const float*)d_in[8];
    const float* Kv     = (const float*)d_in[9];
    const float* W1     = (const float*)d_in[10];
    const float* b1     = (const float*)d_in[11];
    const float* W2     = (const float*)d_in[12];
    const float* b2     = (const float*)d_in[13];
    const float* W3     = (const float*)d_in[14];
    const float* b3     = (const float*)d_in[15];
    const float* W4     = (const float*)d_in[16];
    const float* b4     = (const float*)d_in[17];
    float* out = (float*)d_out;

    joint_kernel<<<BATCH / 64, 512, 0, stream>>>(
        SS, Alphas, K0s, K1s, L0s, L1s, Ms, I, Bv, Kv,
        W1, b1, W2, b2, W3, b3, W4, b4, out);
}

// Round 4
// 103.826 us; speedup vs baseline: 3.1371x; 1.0530x over previous
//
#include <hip/hip_runtime.h>
#include <math.h>

#define BATCH 65536
#define DT_C 0.0166667f
#define NN_RATIO_C 0.3f

typedef __bf16 bf16x8 __attribute__((ext_vector_type(8)));
typedef unsigned short us8 __attribute__((ext_vector_type(8)));
typedef unsigned short us4 __attribute__((ext_vector_type(4)));
typedef float f32x4 __attribute__((ext_vector_type(4)));

union FragU { us8 u; bf16x8 b; };

__device__ __forceinline__ unsigned short f2bf(float f) {
    union { __bf16 h; unsigned short u; } v;
    v.h = (__bf16)f;            // hardware RTNE cvt (v_cvt_pk_bf16_f32)
    return v.u;
}
__device__ __forceinline__ float lrelu(float x) { return x > 0.0f ? x : 0.01f * x; }

// Block = 512 threads = 8 waves; wave w == muscle w; 128 batch rows per block
// (512 blocks -> 2 blocks/CU, ~4 waves/SIMD). Each loop iteration runs TWO
// independent 16-row streams (p=0,1) in separate LDS regions so one stream's
// LDS round-trip latency hides behind the other's MFMA/global-load latency.
// Same-wave DS ops execute in order -> no explicit lgkmcnt(0) barriers needed;
// the compiler inserts counting waits for the loaded registers only.
// MFMA orientation (verified R3, absmax 3.9e-3): D[o][b] = sum_i W[o][i]*X[b][i]
//   A-frag = W[o=t*16+n16][i=quad*8+j], B-frag = X[b=n16][i=quad*8+j],
//   D lane = col b=n16, rows o=quad*4+reg.
__global__ __launch_bounds__(512) void joint_kernel(
    const float* __restrict__ SS, const float* __restrict__ Alphas,
    const float* __restrict__ K0s, const float* __restrict__ K1s,
    const float* __restrict__ L0s, const float* __restrict__ L1s,
    const float* __restrict__ Ms, const float* __restrict__ Ivec,
    const float* __restrict__ Bv, const float* __restrict__ Kv,
    const float* __restrict__ W1, const float* __restrict__ b1,
    const float* __restrict__ W2, const float* __restrict__ b2,
    const float* __restrict__ W3, const float* __restrict__ b3,
    const float* __restrict__ W4, const float* __restrict__ b4,
    float* __restrict__ out)
{
    __shared__ unsigned short Xbuf[16][640];   // [wave*2+stream][16 rows * 40]
    __shared__ float red_k[8][128];
    __shared__ float red_bf[8][128];

    const int tid  = threadIdx.x;
    const int lane = tid & 63;
    const int w    = tid >> 6;
    const int m    = __builtin_amdgcn_readfirstlane(w);
    const int n16  = lane & 15;
    const int quad = lane >> 4;

    const float ms = Ms[m];
    const float k0 = K0s[m], k1 = K1s[m], l0 = L0s[m], l1 = L1s[m];
    const float b4m = b4[m];

    // ---- weight fragments (loaded once per wave) ----
    FragU w1f[2], w2f[2], w3f[2];
    f32x4 bias1[2], bias2[2], bias3[2];
    #pragma unroll
    for (int t = 0; t < 2; ++t) {
        const int o = t * 16 + n16;
        const float* p2 = W2 + m * 1024 + o * 32 + quad * 8;
        const float* p3 = W3 + m * 1024 + o * 32 + quad * 8;
        f32x4 a2 = *(const f32x4*)p2, c2 = *(const f32x4*)(p2 + 4);
        f32x4 a3 = *(const f32x4*)p3, c3 = *(const f32x4*)(p3 + 4);
        #pragma unroll
        for (int j = 0; j < 4; ++j) {
            w2f[t].u[j] = f2bf(a2[j]); w2f[t].u[4 + j] = f2bf(c2[j]);
            w3f[t].u[j] = f2bf(a3[j]); w3f[t].u[4 + j] = f2bf(c3[j]);
        }
        us8 z = {0,0,0,0,0,0,0,0};
        w1f[t].u = z;
        if (quad == 0) {
            const float* p1 = W1 + m * 96 + o * 3;
            w1f[t].u[0] = f2bf(p1[0]);
            w1f[t].u[1] = f2bf(p1[1]);
            w1f[t].u[2] = f2bf(p1[2]);
        }
        bias1[t] = *(const f32x4*)(b1 + m * 32 + t * 16 + quad * 4);
        bias2[t] = *(const f32x4*)(b2 + m * 32 + t * 16 + quad * 4);
        bias3[t] = *(const f32x4*)(b3 + m * 32 + t * 16 + quad * 4);
    }
    const f32x4 w4a = *(const f32x4*)(W4 + m * 32 + quad * 4);
    const f32x4 w4b = *(const f32x4*)(W4 + m * 32 + 16 + quad * 4);

    unsigned short* const X0 = &Xbuf[2 * w][0];
    unsigned short* const X1 = &Xbuf[2 * w + 1][0];

    #pragma unroll 1
    for (int s = 0; s < 8; s += 2) {
        float lv[2], dlv[2], av[2];
        FragU xf[2];
        #pragma unroll
        for (int p = 0; p < 2; ++p) {
            const int bb = blockIdx.x * 128 + (s + p) * 16 + n16;
            const float2 ssv = *(const float2*)&SS[2 * bb];
            float a = Alphas[8 * bb + m];
            a = fminf(fmaxf(a, 0.0f), 1.0f);
            av[p]  = a;
            lv[p]  = ssv.x * ms;
            dlv[p] = ssv.y * ms;
            us8 z = {0,0,0,0,0,0,0,0};
            xf[p].u = z;
            if (quad == 0) {
                xf[p].u[0] = f2bf(lv[p]);
                xf[p].u[1] = f2bf(dlv[p]);
                xf[p].u[2] = f2bf(a);
            }
        }

        f32x4 acc0[2], acc1[2];
        #pragma unroll
        for (int p = 0; p < 2; ++p) {
            acc0[p] = __builtin_amdgcn_mfma_f32_16x16x32_bf16(w1f[0].b, xf[p].b, bias1[0], 0, 0, 0);
            acc1[p] = __builtin_amdgcn_mfma_f32_16x16x32_bf16(w1f[1].b, xf[p].b, bias1[1], 0, 0, 0);
        }
        #pragma unroll
        for (int p = 0; p < 2; ++p) {
            unsigned short* X = p ? X1 : X0;
            us4 st0, st1;
            #pragma unroll
            for (int r = 0; r < 4; ++r) {
                st0[r] = f2bf(lrelu(acc0[p][r]));
                st1[r] = f2bf(lrelu(acc1[p][r]));
            }
            *(us4*)&X[n16 * 40 + quad * 4]      = st0;
            *(us4*)&X[n16 * 40 + 16 + quad * 4] = st1;
        }

        FragU hf[2];
        #pragma unroll
        for (int p = 0; p < 2; ++p)
            hf[p].u = *(const us8*)&((p ? X1 : X0)[n16 * 40 + quad * 8]);
        #pragma unroll
        for (int p = 0; p < 2; ++p) {
            acc0[p] = __builtin_amdgcn_mfma_f32_16x16x32_bf16(w2f[0].b, hf[p].b, bias2[0], 0, 0, 0);
            acc1[p] = __builtin_amdgcn_mfma_f32_16x16x32_bf16(w2f[1].b, hf[p].b, bias2[1], 0, 0, 0);
        }
        #pragma unroll
        for (int p = 0; p < 2; ++p) {
            unsigned short* X = p ? X1 : X0;
            us4 st0, st1;
            #pragma unroll
            for (int r = 0; r < 4; ++r) {
                st0[r] = f2bf(lrelu(acc0[p][r]));
                st1[r] = f2bf(lrelu(acc1[p][r]));
            }
            *(us4*)&X[n16 * 40 + quad * 4]      = st0;
            *(us4*)&X[n16 * 40 + 16 + quad * 4] = st1;
        }

        #pragma unroll
        for (int p = 0; p < 2; ++p)
            hf[p].u = *(const us8*)&((p ? X1 : X0)[n16 * 40 + quad * 8]);
        #pragma unroll
        for (int p = 0; p < 2; ++p) {
            acc0[p] = __builtin_amdgcn_mfma_f32_16x16x32_bf16(w3f[0].b, hf[p].b, bias3[0], 0, 0, 0);
            acc1[p] = __builtin_amdgcn_mfma_f32_16x16x32_bf16(w3f[1].b, hf[p].b, bias3[1], 0, 0, 0);
        }

        float dot[2];
        #pragma unroll
        for (int p = 0; p < 2; ++p) {
            float d = 0.0f;
            #pragma unroll
            for (int r = 0; r < 4; ++r) {
                d += lrelu(acc0[p][r]) * w4a[r];
                d += lrelu(acc1[p][r]) * w4b[r];
            }
            d += __shfl_xor(d, 16, 64);
            d += __shfl_xor(d, 32, 64);
            dot[p] = d;
        }

        if (quad == 0) {
            #pragma unroll
            for (int p = 0; p < 2; ++p) {
                const float x2 = 2.0f * (dot[p] + b4m);
                const float e2x = __expf(x2);
                const float nn = (1.0f - 2.0f / (e2x + 1.0f)) * NN_RATIO_C;
                const float kk = k0 + k1 * av[p];
                red_k[w][(s + p) * 16 + n16]  = kk * ms * ms;
                red_bf[w][(s + p) * 16 + n16] =
                    (kk * (l0 + l1 * av[p] - fabsf(lv[p])) + k1 * l1 * av[p] * av[p] * nn) * ms;
            }
        }
    }

    __syncthreads();

    if (tid < 128) {
        float Ksum = 0.0f, BFsum = 0.0f;
        #pragma unroll
        for (int mm = 0; mm < 8; ++mm) {
            Ksum  += red_k[mm][tid];
            BFsum += red_bf[mm][tid];
        }

        const int b = blockIdx.x * 128 + tid;
        const float2 ssv = *(const float2*)&SS[2 * b];
        const float s0 = ssv.x, s1 = ssv.y;
        const float I  = Ivec[0];
        const float bv = Bv[0];
        const float kv = Kv[0];
        const float inv_I = 1.0f / I;

        const float A10 = -(Ksum + kv) * inv_I;
        const float D   = 2.0f * sqrtf(Ksum * I);
        const float A11 = -(D + bv) * inv_I;
        const float B10 = BFsum * inv_I;

        // Reduced 3x3 expm (verified R1-R3): M=[[0,DT,0],[A10*DT,A11*DT,B10*DT],[0,0,0]]
        const float m01 = DT_C;
        const float m10 = A10 * DT_C, m11 = A11 * DT_C, m12 = B10 * DT_C;

        float p00 = 0.0f, p01 = m01, p02 = 0.0f;
        float p10 = m10,  p11 = m11, p12 = m12;
        float t00 = p00, t01 = p01, t02 = p02;
        float t10 = p10, t11 = p11, t12 = p12;
        #pragma unroll
        for (int k = 2; k <= 16; ++k) {
            float inv = 1.0f / (float)k;
            float q00 = (p01 * m10) * inv;
            float q01 = (p00 * m01 + p01 * m11) * inv;
            float q02 = (p01 * m12) * inv;
            float q10 = (p11 * m10) * inv;
            float q11 = (p10 * m01 + p11 * m11) * inv;
            float q12 = (p11 * m12) * inv;
            p00 = q00; p01 = q01; p02 = q02;
            p10 = q10; p11 = q11; p12 = q12;
            t00 += p00; t01 += p01; t02 += p02;
            t10 += p10; t11 += p11; t12 += p12;
        }
        const float E00 = 1.0f + t00, E01 = t01, c0 = t02;
        const float E10 = t10,        E11 = 1.0f + t11, c1 = t12;

        const float o0 = E00 * s0 + E01 * s1 + c0;
        const float o1 = E10 * s0 + E11 * s1 + c1;

        out[b] = o0;                     // output 0: SSout[:,0:1]
        out[BATCH + 2 * b]     = o0;     // output 1: SSout[:,:,0]
        out[BATCH + 2 * b + 1] = o1;
    }
}

extern "C" void kernel_launch(void* const* d_in, const int* in_sizes, int n_in,
                              void* d_out, int out_size, void* d_ws, size_t ws_size,
                              hipStream_t stream) {
    const float* SS     = (const float*)d_in[0];
    const float* Alphas = (const float*)d_in[1];
    const float* K0s    = (const float*)d_in[2];
    const float* K1s    = (const float*)d_in[3];
    const float* L0s    = (const float*)d_in[4];
    const float* L1s    = (const float*)d_in[5];
    const float* Ms     = (const float*)d_in[6];
    const float* I      = (const float*)d_in[7];
    const float* Bv     = (const float*)d_in[8];
    const float* Kv     = (const float*)d_in[9];
    const float* W1     = (const float*)d_in[10];
    const float* b1     = (const float*)d_in[11];
    const float* W2     = (const float*)d_in[12];
    const float* b2     = (const float*)d_in[13];
    const float* W3     = (const float*)d_in[14];
    const float* b3     = (const float*)d_in[15];
    const float* W4     = (const float*)d_in[16];
    const float* b4     = (const float*)d_in[17];
    float* out = (float*)d_out;

    joint_kernel<<<BATCH / 128, 512, 0, stream>>>(
        SS, Alphas, K0s, K1s, L0s, L1s, Ms, I, Bv, Kv,
        W1, b1, W2, b2, W3, b3, W4, b4, out);
}